// Round 4
// baseline (117.860 us; speedup 1.0000x reference)
//
#include <hip/hip_runtime.h>
#include <hip/hip_bf16.h>

#define B_    2
#define SQ_   2048
#define SK_   2048
#define NH_   16
#define DH_   64
#define WIN_  256
#define NEG_  -30000.0f

typedef __bf16 bf16_t;
typedef bf16_t bf16x8 __attribute__((ext_vector_type(8)));
typedef bf16_t bf16x4 __attribute__((ext_vector_type(4)));
typedef float  f32x4  __attribute__((ext_vector_type(4)));
typedef short  s16x4  __attribute__((ext_vector_type(4)));

// 64-element rows + 8 pad = 144 B stride: b128/b64 accesses stay 16B-aligned
#define KSTRIDE 72
#define VSTRIDE 72

__global__ __launch_bounds__(256, 4)
void fa_fwd(const float* __restrict__ qg, const float* __restrict__ kvg,
            float* __restrict__ outg) {
  const int tid  = threadIdx.x;
  const int wid  = tid >> 6;      // 0..3, each wave owns 16 q-rows
  const int lane = tid & 63;
  const int quad = lane >> 4;
  const int li   = lane & 15;

  const int bid = blockIdx.x;
  const int qb  = bid >> 5;   // 32 q-blocks of 64 rows
  const int bh  = bid & 31;   // same bh -> same XCD (kv L2 locality)
  const int b   = bh >> 4;
  const int h   = bh & 15;

  const int q0b = qb * 64;
  const int q0  = q0b + wid * 16;

  __shared__ __align__(16) bf16_t sK [2][64 * KSTRIDE];   // K tiles [key][d]
  __shared__ __align__(16) bf16_t sVT[2][64 * VSTRIDE];   // V^T tiles [d][key^swz]

  // ---- Q fragments (16 rows), scale * log2(e) folded ----
  const float qscale = 0.125f * 1.44269504088896340736f;
  const float* qrow = qg + ((size_t)((b * SQ_ + q0 + li) * NH_ + h)) * DH_;
  bf16x8 qfrag[2];
#pragma unroll
  for (int c = 0; c < 2; ++c) {
    f32x4 a0 = *(const f32x4*)(qrow + c * 32 + quad * 8);
    f32x4 a1 = *(const f32x4*)(qrow + c * 32 + quad * 8 + 4);
#pragma unroll
    for (int i = 0; i < 4; ++i) {
      qfrag[c][i]     = (bf16_t)(a0[i] * qscale);
      qfrag[c][i + 4] = (bf16_t)(a1[i] * qscale);
    }
  }

  f32x4 oacc[4];
#pragma unroll
  for (int t = 0; t < 4; ++t) { f32x4 z = {0.f, 0.f, 0.f, 0.f}; oacc[t] = z; }
  float m = NEG_, l = 0.f;   // l is a per-lane PARTIAL (reduced in epilogue)

  // block-uniform 64-aligned key range
  int klo = q0b - WIN_; if (klo < 0) klo = 0;
  int khi = q0b + 63 + WIN_ + 1; if (khi > SK_) khi = SK_;

  const float* kbase = kvg + (size_t)b * SK_ * 2 * NH_ * DH_ + (size_t)h * DH_;
  const float* vbase = kbase + NH_ * DH_;
  const size_t krow_stride = 2 * NH_ * DH_;

  // staging: 256 threads cover 64 keys x 64 d (16 floats each of K and V)
  const int skey = tid >> 2;         // 0..63
  const int sd0  = (tid & 3) * 16;   // 0,16,32,48

  f32x4 ka[4], va[4];
  // ---- prologue: load + stage tile 0 into buf 0 ----
  {
    const float* kr = kbase + (size_t)(klo + skey) * krow_stride + sd0;
    const float* vr = vbase + (size_t)(klo + skey) * krow_stride + sd0;
#pragma unroll
    for (int i = 0; i < 4; ++i) {
      ka[i] = *(const f32x4*)(kr + 4 * i);
      va[i] = *(const f32x4*)(vr + 4 * i);
    }
  }
  {
#pragma unroll
    for (int hh = 0; hh < 2; ++hh) {
      bf16x8 wk;
#pragma unroll
      for (int i = 0; i < 4; ++i) {
        wk[i] = (bf16_t)ka[2 * hh][i]; wk[i + 4] = (bf16_t)ka[2 * hh + 1][i];
      }
      *(bf16x8*)(&sK[0][skey * KSTRIDE + sd0 + 8 * hh]) = wk;
      const int dbase = sd0 + 8 * hh;
      const int vcol  = skey ^ (((dbase >> 3) & 7) << 3);
#pragma unroll
      for (int i = 0; i < 4; ++i) {
        sVT[0][(dbase + i)     * VSTRIDE + vcol] = (bf16_t)va[2 * hh][i];
        sVT[0][(dbase + 4 + i) * VSTRIDE + vcol] = (bf16_t)va[2 * hh + 1][i];
      }
    }
  }
  __syncthreads();

  int buf = 0;
  for (int kk = klo; kk < khi; kk += 64) {
    const bool nxt = (kk + 64 < khi);   // block-uniform
    // ---- issue next tile's global loads (in flight across compute) ----
    if (nxt) {
      const float* kr = kbase + (size_t)(kk + 64 + skey) * krow_stride + sd0;
      const float* vr = vbase + (size_t)(kk + 64 + skey) * krow_stride + sd0;
#pragma unroll
      for (int i = 0; i < 4; ++i) {
        ka[i] = *(const f32x4*)(kr + 4 * i);
        va[i] = *(const f32x4*)(vr + 4 * i);
      }
    }

    // ---- compute only if this tile intersects the wave's window ----
    if (kk + 63 >= q0 - WIN_ && kk <= q0 + 15 + WIN_) {
      // S^T = K . Q^T : 4 key subtiles, D=64 as two K=32 chunks
      f32x4 sc[4];
#pragma unroll
      for (int s = 0; s < 4; ++s) {
        bf16x8 kf0 = *(const bf16x8*)(&sK[buf][(s * 16 + li) * KSTRIDE + quad * 8]);
        bf16x8 kf1 = *(const bf16x8*)(&sK[buf][(s * 16 + li) * KSTRIDE + 32 + quad * 8]);
        f32x4 acc = {0.f, 0.f, 0.f, 0.f};
        acc = __builtin_amdgcn_mfma_f32_16x16x32_bf16(kf0, qfrag[0], acc, 0, 0, 0);
        acc = __builtin_amdgcn_mfma_f32_16x16x32_bf16(kf1, qfrag[1], acc, 0, 0, 0);
        sc[s] = acc;
      }
      // window mask only on boundary tiles (wave-uniform branch)
      if (kk < q0 - 241 || kk > q0 + 193) {
        const int qa = q0 + li;
#pragma unroll
        for (int s = 0; s < 4; ++s)
#pragma unroll
          for (int r = 0; r < 4; ++r) {
            int key = kk + s * 16 + quad * 4 + r;
            unsigned dd = (unsigned)(key - qa + WIN_);
            if (dd > 2u * WIN_) sc[s][r] = NEG_;
          }
      }
      // local tile max (no cross-lane reduce needed for the defer test:
      // __all over the wave covers all lanes of every column group)
      float tl = NEG_;
#pragma unroll
      for (int s = 0; s < 4; ++s)
        tl = fmaxf(tl, fmaxf(fmaxf(sc[s][0], sc[s][1]), fmaxf(sc[s][2], sc[s][3])));

      // T13 defer-max: skip rescale while max growth <= 8 (log2 domain)
      const bool defer = (__all(tl <= m + 8.0f) != 0);   // wave-uniform
      float mnew = m;
      if (!defer) {
        float tr = fmaxf(tl, __shfl_xor(tl, 16));
        tr = fmaxf(tr, __shfl_xor(tr, 32));
        mnew = fmaxf(m, tr);
      }

      // P stays in-lane: QK^T C-layout == 16x16x16 MFMA A-layout per key subtile
      float psum = 0.f;
      bf16x4 pa[4];
#pragma unroll
      for (int s = 0; s < 4; ++s) {
        float p0 = exp2f(sc[s][0] - mnew);
        float p1 = exp2f(sc[s][1] - mnew);
        float p2 = exp2f(sc[s][2] - mnew);
        float p3 = exp2f(sc[s][3] - mnew);
        psum += (p0 + p1) + (p2 + p3);
        pa[s][0] = (bf16_t)p0; pa[s][1] = (bf16_t)p1;
        pa[s][2] = (bf16_t)p2; pa[s][3] = (bf16_t)p3;
      }

      if (!defer) {
        const float alpha = exp2f(m - mnew);
        float al[4];
#pragma unroll
        for (int r = 0; r < 4; ++r) al[r] = __shfl(alpha, quad * 4 + r);
#pragma unroll
        for (int t = 0; t < 4; ++t) {
          oacc[t][0] *= al[0]; oacc[t][1] *= al[1];
          oacc[t][2] *= al[2]; oacc[t][3] *= al[3];
        }
        l = l * alpha + psum;   // per-lane partial, column-uniform alpha
        m = mnew;
      } else {
        l += psum;
      }

      // O += P . V : K=16 MFMA per key subtile, P from registers (no transpose)
#pragma unroll
      for (int s = 0; s < 4; ++s) {
        const s16x4 pas = __builtin_bit_cast(s16x4, pa[s]);
#pragma unroll
        for (int t = 0; t < 4; ++t) {
          const int d  = 16 * t + li;
          const int c8 = ((2 * t + (li >> 3)) & 7) << 3;
          s16x4 vb = *(const s16x4*)(&sVT[buf][d * VSTRIDE + ((s * 16 + quad * 4) ^ c8)]);
          oacc[t] = __builtin_amdgcn_mfma_f32_16x16x16bf16_1k(pas, vb, oacc[t], 0, 0, 0);
        }
      }
    }

    // ---- stage next tile into the other buffer ----
    if (nxt) {
#pragma unroll
      for (int hh = 0; hh < 2; ++hh) {
        bf16x8 wk;
#pragma unroll
        for (int i = 0; i < 4; ++i) {
          wk[i] = (bf16_t)ka[2 * hh][i]; wk[i + 4] = (bf16_t)ka[2 * hh + 1][i];
        }
        *(bf16x8*)(&sK[buf ^ 1][skey * KSTRIDE + sd0 + 8 * hh]) = wk;
        const int dbase = sd0 + 8 * hh;
        const int vcol  = skey ^ (((dbase >> 3) & 7) << 3);
#pragma unroll
        for (int i = 0; i < 4; ++i) {
          sVT[buf ^ 1][(dbase + i)     * VSTRIDE + vcol] = (bf16_t)va[2 * hh][i];
          sVT[buf ^ 1][(dbase + 4 + i) * VSTRIDE + vcol] = (bf16_t)va[2 * hh + 1][i];
        }
      }
    }
    __syncthreads();   // the single barrier per iteration
    buf ^= 1;
  }

  // ---- epilogue: reduce the per-lane l partials, then normalize ----
  l += __shfl_xor(l, 16);
  l += __shfl_xor(l, 32);
  float rl[4];
#pragma unroll
  for (int r = 0; r < 4; ++r) {
    float lv = __shfl(l, quad * 4 + r);
    rl[r] = 1.0f / lv;
  }
  float* orow = outg + ((size_t)((b * SQ_ + q0) * NH_ + h)) * DH_;
#pragma unroll
  for (int t = 0; t < 4; ++t)
#pragma unroll
    for (int r = 0; r < 4; ++r)
      orow[(size_t)(quad * 4 + r) * (NH_ * DH_) + 16 * t + li] = oacc[t][r] * rl[r];
}

extern "C" void kernel_launch(void* const* d_in, const int* in_sizes, int n_in,
                              void* d_out, int out_size, void* d_ws, size_t ws_size,
                              hipStream_t stream) {
  (void)in_sizes; (void)n_in; (void)out_size; (void)d_ws; (void)ws_size;
  const float* q  = (const float*)d_in[0];
  const float* kv = (const float*)d_in[1];
  float* out = (float*)d_out;
  dim3 grid(B_ * NH_ * (SQ_ / 64));  // 1024 blocks x 4 waves = 4 indep blocks/CU
  fa_fwd<<<grid, 256, 0, stream>>>(q, kv, out);
}

// Round 5
// 117.695 us; speedup vs baseline: 1.0014x; 1.0014x over previous
//
#include <hip/hip_runtime.h>
#include <hip/hip_bf16.h>

#define B_    2
#define SQ_   2048
#define SK_   2048
#define NH_   16
#define DH_   64
#define WIN_  256
#define NEG_  -30000.0f

typedef __bf16 bf16_t;
typedef bf16_t bf16x8 __attribute__((ext_vector_type(8)));
typedef bf16_t bf16x4 __attribute__((ext_vector_type(4)));
typedef float  f32x4  __attribute__((ext_vector_type(4)));
typedef short  s16x4  __attribute__((ext_vector_type(4)));

// 64-element rows + 8 pad = 144 B stride: b128/b64 accesses stay 16B-aligned
#define KSTRIDE 72
#define VSTRIDE 72

__global__ __launch_bounds__(256, 4)
void fa_fwd(const float* __restrict__ qg, const float* __restrict__ kvg,
            float* __restrict__ outg) {
  const int tid  = threadIdx.x;
  const int wid  = tid >> 6;      // 0..3, each wave owns 16 q-rows
  const int lane = tid & 63;
  const int quad = lane >> 4;
  const int li   = lane & 15;

  const int bid = blockIdx.x;
  const int qb  = bid >> 5;   // 32 q-blocks of 64 rows
  const int bh  = bid & 31;   // same bh -> same XCD (kv L2 locality)
  const int b   = bh >> 4;
  const int h   = bh & 15;

  const int q0b = qb * 64;
  const int q0  = q0b + wid * 16;

  __shared__ __align__(16) bf16_t sK [2][64 * KSTRIDE];   // K tiles [key][d]
  __shared__ __align__(16) bf16_t sVT[2][64 * VSTRIDE];   // V^T tiles [d][key^swz]

  // ---- Q fragments (16 rows), scale * log2(e) folded ----
  const float qscale = 0.125f * 1.44269504088896340736f;
  const float* qrow = qg + ((size_t)((b * SQ_ + q0 + li) * NH_ + h)) * DH_;
  bf16x8 qfrag[2];
#pragma unroll
  for (int c = 0; c < 2; ++c) {
    f32x4 a0 = *(const f32x4*)(qrow + c * 32 + quad * 8);
    f32x4 a1 = *(const f32x4*)(qrow + c * 32 + quad * 8 + 4);
#pragma unroll
    for (int i = 0; i < 4; ++i) {
      qfrag[c][i]     = (bf16_t)(a0[i] * qscale);
      qfrag[c][i + 4] = (bf16_t)(a1[i] * qscale);
    }
  }

  f32x4 oacc[4];
#pragma unroll
  for (int t = 0; t < 4; ++t) { f32x4 z = {0.f, 0.f, 0.f, 0.f}; oacc[t] = z; }
  float m = NEG_, l = 0.f;   // l is a per-lane PARTIAL (reduced in epilogue)

  // block-uniform 64-aligned key range
  int klo = q0b - WIN_; if (klo < 0) klo = 0;
  int khi = q0b + 63 + WIN_ + 1; if (khi > SK_) khi = SK_;
  const int nt = (khi - klo + 63) >> 6;   // block-uniform tile count

  const float* kbase = kvg + (size_t)b * SK_ * 2 * NH_ * DH_ + (size_t)h * DH_;
  const float* vbase = kbase + NH_ * DH_;
  const size_t krow_stride = 2 * NH_ * DH_;

  // staging: 256 threads cover 64 keys x 64 d (16 floats each of K and V)
  const int skey = tid >> 2;         // 0..63
  const int sd0  = (tid & 3) * 16;   // 0,16,32,48

  f32x4 ka[4], va[4];

  auto issue_loads = [&](int kt) {
    const float* kr = kbase + (size_t)(kt + skey) * krow_stride + sd0;
    const float* vr = vbase + (size_t)(kt + skey) * krow_stride + sd0;
#pragma unroll
    for (int i = 0; i < 4; ++i) {
      ka[i] = *(const f32x4*)(kr + 4 * i);
      va[i] = *(const f32x4*)(vr + 4 * i);
    }
  };

  auto stage = [&](int bb) {
#pragma unroll
    for (int hh = 0; hh < 2; ++hh) {
      bf16x8 wk;
#pragma unroll
      for (int i = 0; i < 4; ++i) {
        wk[i] = (bf16_t)ka[2 * hh][i]; wk[i + 4] = (bf16_t)ka[2 * hh + 1][i];
      }
      *(bf16x8*)(&sK[bb][skey * KSTRIDE + sd0 + 8 * hh]) = wk;
      const int dbase = sd0 + 8 * hh;
      const int vcol  = skey ^ (((dbase >> 3) & 7) << 3);
#pragma unroll
      for (int i = 0; i < 4; ++i) {
        sVT[bb][(dbase + i)     * VSTRIDE + vcol] = (bf16_t)va[2 * hh][i];
        sVT[bb][(dbase + 4 + i) * VSTRIDE + vcol] = (bf16_t)va[2 * hh + 1][i];
      }
    }
  };

  // ---- prologue: tile 0 -> buf 0; issue tile 1 (in flight across barrier) ----
  issue_loads(klo);
  stage(0);
  if (nt > 1) issue_loads(klo + 64);
  __syncthreads();

  int buf = 0;
  for (int t = 0; t < nt; ++t) {
    const int kk = klo + t * 64;
    // ---- stage tile t+1 (its loads are a full iteration old: no vmcnt stall),
    //      then immediately re-issue loads for tile t+2 into the same regs ----
    if (t + 1 < nt) stage(buf ^ 1);
    if (t + 2 < nt) issue_loads(klo + (t + 2) * 64);

    // ---- compute only if this tile intersects the wave's window ----
    if (kk + 63 >= q0 - WIN_ && kk <= q0 + 15 + WIN_) {
      // S^T = K . Q^T : 4 key subtiles, D=64 as two K=32 chunks
      f32x4 sc[4];
      __builtin_amdgcn_s_setprio(1);
#pragma unroll
      for (int s = 0; s < 4; ++s) {
        bf16x8 kf0 = *(const bf16x8*)(&sK[buf][(s * 16 + li) * KSTRIDE + quad * 8]);
        bf16x8 kf1 = *(const bf16x8*)(&sK[buf][(s * 16 + li) * KSTRIDE + 32 + quad * 8]);
        f32x4 acc = {0.f, 0.f, 0.f, 0.f};
        acc = __builtin_amdgcn_mfma_f32_16x16x32_bf16(kf0, qfrag[0], acc, 0, 0, 0);
        acc = __builtin_amdgcn_mfma_f32_16x16x32_bf16(kf1, qfrag[1], acc, 0, 0, 0);
        sc[s] = acc;
      }
      __builtin_amdgcn_s_setprio(0);
      // window mask only on boundary tiles (wave-uniform branch)
      if (kk < q0 - 241 || kk > q0 + 193) {
        const int qa = q0 + li;
#pragma unroll
        for (int s = 0; s < 4; ++s)
#pragma unroll
          for (int r = 0; r < 4; ++r) {
            int key = kk + s * 16 + quad * 4 + r;
            unsigned dd = (unsigned)(key - qa + WIN_);
            if (dd > 2u * WIN_) sc[s][r] = NEG_;
          }
      }
      // local tile max (the defer ballot covers all lanes of every column)
      float tl = NEG_;
#pragma unroll
      for (int s = 0; s < 4; ++s)
        tl = fmaxf(tl, fmaxf(fmaxf(sc[s][0], sc[s][1]), fmaxf(sc[s][2], sc[s][3])));

      // T13 defer-max: skip rescale while max growth <= 8 (log2 domain)
      const bool defer = (__all(tl <= m + 8.0f) != 0);   // wave-uniform
      float mnew = m;
      if (!defer) {
        float tr = fmaxf(tl, __shfl_xor(tl, 16));
        tr = fmaxf(tr, __shfl_xor(tr, 32));
        mnew = fmaxf(m, tr);
      }

      // P stays in-lane: QK^T C-layout == 16x16x16 MFMA A-layout per key subtile
      float psum = 0.f;
      bf16x4 pa[4];
#pragma unroll
      for (int s = 0; s < 4; ++s) {
        float p0 = exp2f(sc[s][0] - mnew);
        float p1 = exp2f(sc[s][1] - mnew);
        float p2 = exp2f(sc[s][2] - mnew);
        float p3 = exp2f(sc[s][3] - mnew);
        psum += (p0 + p1) + (p2 + p3);
        pa[s][0] = (bf16_t)p0; pa[s][1] = (bf16_t)p1;
        pa[s][2] = (bf16_t)p2; pa[s][3] = (bf16_t)p3;
      }

      if (!defer) {
        const float alpha = exp2f(m - mnew);
        float al[4];
#pragma unroll
        for (int r = 0; r < 4; ++r) al[r] = __shfl(alpha, quad * 4 + r);
#pragma unroll
        for (int t2 = 0; t2 < 4; ++t2) {
          oacc[t2][0] *= al[0]; oacc[t2][1] *= al[1];
          oacc[t2][2] *= al[2]; oacc[t2][3] *= al[3];
        }
        l = l * alpha + psum;   // per-lane partial, column-uniform alpha
        m = mnew;
      } else {
        l += psum;
      }

      // O += P . V : K=16 MFMA per key subtile, P from registers (no transpose)
      __builtin_amdgcn_s_setprio(1);
#pragma unroll
      for (int s = 0; s < 4; ++s) {
        const s16x4 pas = __builtin_bit_cast(s16x4, pa[s]);
#pragma unroll
        for (int t2 = 0; t2 < 4; ++t2) {
          const int d  = 16 * t2 + li;
          const int c8 = ((2 * t2 + (li >> 3)) & 7) << 3;
          s16x4 vb = *(const s16x4*)(&sVT[buf][d * VSTRIDE + ((s * 16 + quad * 4) ^ c8)]);
          oacc[t2] = __builtin_amdgcn_mfma_f32_16x16x16bf16_1k(pas, vb, oacc[t2], 0, 0, 0);
        }
      }
      __builtin_amdgcn_s_setprio(0);
    }

    __syncthreads();   // the single barrier per iteration
    buf ^= 1;
  }

  // ---- epilogue: reduce the per-lane l partials, then normalize ----
  l += __shfl_xor(l, 16);
  l += __shfl_xor(l, 32);
  float rl[4];
#pragma unroll
  for (int r = 0; r < 4; ++r) {
    float lv = __shfl(l, quad * 4 + r);
    rl[r] = 1.0f / lv;
  }
  float* orow = outg + ((size_t)((b * SQ_ + q0) * NH_ + h)) * DH_;
#pragma unroll
  for (int t = 0; t < 4; ++t)
#pragma unroll
    for (int r = 0; r < 4; ++r)
      orow[(size_t)(quad * 4 + r) * (NH_ * DH_) + 16 * t + li] = oacc[t][r] * rl[r];
}

extern "C" void kernel_launch(void* const* d_in, const int* in_sizes, int n_in,
                              void* d_out, int out_size, void* d_ws, size_t ws_size,
                              hipStream_t stream) {
  (void)in_sizes; (void)n_in; (void)out_size; (void)d_ws; (void)ws_size;
  const float* q  = (const float*)d_in[0];
  const float* kv = (const float*)d_in[1];
  float* out = (float*)d_out;
  dim3 grid(B_ * NH_ * (SQ_ / 64));  // 1024 blocks x 4 waves = 4 indep blocks/CU
  fa_fwd<<<grid, 256, 0, stream>>>(q, kv, out);
}

// Round 6
// 116.784 us; speedup vs baseline: 1.0092x; 1.0078x over previous
//
#include <hip/hip_runtime.h>
#include <hip/hip_bf16.h>

#define B_    2
#define SQ_   2048
#define SK_   2048
#define NH_   16
#define DH_   64
#define WIN_  256
#define NEG_  -30000.0f

typedef __bf16 bf16_t;
typedef bf16_t bf16x8 __attribute__((ext_vector_type(8)));
typedef bf16_t bf16x4 __attribute__((ext_vector_type(4)));
typedef float  f32x4  __attribute__((ext_vector_type(4)));
typedef float  f32x16 __attribute__((ext_vector_type(16)));

// 64-element rows + 8 pad = 144 B stride: b128/b64 accesses stay 16B-aligned
#define KSTRIDE 72
#define VSTRIDE 72
#define PSTRIDE 72

static __device__ __forceinline__ f32x16 zero16() {
  f32x16 z;
#pragma unroll
  for (int i = 0; i < 16; ++i) z[i] = 0.f;
  return z;
}

__global__ __launch_bounds__(256, 2)
void fa_fwd(const float* __restrict__ qg, const float* __restrict__ kvg,
            float* __restrict__ outg) {
  const int tid  = threadIdx.x;
  const int wid  = tid >> 6;      // 0..3, each wave owns 32 q-rows
  const int lane = tid & 63;
  const int c31  = lane & 31;     // q-column within the wave's 32 rows
  const int hi   = lane >> 5;

  const int bid = blockIdx.x;
  const int qb  = bid >> 5;   // 16 q-blocks of 128 rows
  const int bh  = bid & 31;   // same bh -> same XCD (kv L2 locality)
  const int b   = bh >> 4;
  const int h   = bh & 15;

  const int q0b = qb * 128;
  const int q0  = q0b + wid * 32;

  __shared__ __align__(16) bf16_t sK [2][64 * KSTRIDE];   // K tiles [key][d]
  __shared__ __align__(16) bf16_t sVT[2][64 * VSTRIDE];   // V^T tiles [d][key^swz]
  __shared__ __align__(16) bf16_t sP [4][32 * PSTRIDE];   // per-wave P [q][key]
  bf16_t* plw = sP[wid];

  // ---- Q fragments (32 rows, one q-col per lane), scale * log2(e) folded ----
  const float qscale = 0.125f * 1.44269504088896340736f;
  const float* qrow = qg + ((size_t)((b * SQ_ + q0 + c31) * NH_ + h)) * DH_;
  bf16x8 qfrag[4];   // B-operand: Q[q=c31][d = ds*16 + hi*8 + e]
#pragma unroll
  for (int ds = 0; ds < 4; ++ds) {
    const int d0 = ds * 16 + hi * 8;
    f32x4 a0 = *(const f32x4*)(qrow + d0);
    f32x4 a1 = *(const f32x4*)(qrow + d0 + 4);
#pragma unroll
    for (int i = 0; i < 4; ++i) {
      qfrag[ds][i]     = (bf16_t)(a0[i] * qscale);
      qfrag[ds][i + 4] = (bf16_t)(a1[i] * qscale);
    }
  }

  f32x16 oacc[2];   // O[q-rows (C layout)][d = dt*32 + c31]
  oacc[0] = zero16(); oacc[1] = zero16();
  float m = NEG_, el = 0.f;   // per-lane state for q-column c31

  // block-uniform 64-aligned key range
  int klo = q0b - WIN_; if (klo < 0) klo = 0;
  int khi = q0b + 127 + WIN_ + 1; if (khi > SK_) khi = SK_;
  const int nt = (khi - klo + 63) >> 6;   // block-uniform tile count

  const float* kbase = kvg + (size_t)b * SK_ * 2 * NH_ * DH_ + (size_t)h * DH_;
  const float* vbase = kbase + NH_ * DH_;
  const size_t krow_stride = 2 * NH_ * DH_;

  // staging: 256 threads cover 64 keys x 64 d (16 floats each of K and V)
  const int skey = tid >> 2;         // 0..63
  const int sd0  = (tid & 3) * 16;   // 0,16,32,48

  f32x4 ka[4], va[4];

  auto issue_loads = [&](int kt) {
    const float* kr = kbase + (size_t)(kt + skey) * krow_stride + sd0;
    const float* vr = vbase + (size_t)(kt + skey) * krow_stride + sd0;
#pragma unroll
    for (int i = 0; i < 4; ++i) {
      ka[i] = *(const f32x4*)(kr + 4 * i);
      va[i] = *(const f32x4*)(vr + 4 * i);
    }
  };

  auto stage = [&](int bb) {
#pragma unroll
    for (int hh = 0; hh < 2; ++hh) {
      bf16x8 wk;
#pragma unroll
      for (int i = 0; i < 4; ++i) {
        wk[i] = (bf16_t)ka[2 * hh][i]; wk[i + 4] = (bf16_t)ka[2 * hh + 1][i];
      }
      *(bf16x8*)(&sK[bb][skey * KSTRIDE + sd0 + 8 * hh]) = wk;
      const int dbase = sd0 + 8 * hh;
      const int vcol  = skey ^ (((dbase >> 3) & 7) << 3);
#pragma unroll
      for (int i = 0; i < 4; ++i) {
        sVT[bb][(dbase + i)     * VSTRIDE + vcol] = (bf16_t)va[2 * hh][i];
        sVT[bb][(dbase + 4 + i) * VSTRIDE + vcol] = (bf16_t)va[2 * hh + 1][i];
      }
    }
  };

  // ---- prologue: tile 0 -> buf 0; issue tile 1 (in flight across barrier) ----
  issue_loads(klo);
  stage(0);
  if (nt > 1) issue_loads(klo + 64);
  __syncthreads();

  int buf = 0;
  for (int t = 0; t < nt; ++t) {
    const int kk = klo + t * 64;
    // stage tile t+1 (loads are a full iteration old), then issue t+2
    if (t + 1 < nt) stage(buf ^ 1);
    if (t + 2 < nt) issue_loads(klo + (t + 2) * 64);

    // ---- compute only if this tile intersects the wave's window ----
    if (kk + 63 >= q0 - WIN_ && kk <= q0 + 31 + WIN_) {
      // S^T = K . Q^T : two 32-key halves, D=64 as four K=16 chunks
      f32x16 sc[2];
      __builtin_amdgcn_s_setprio(1);
#pragma unroll
      for (int kh = 0; kh < 2; ++kh) {
        f32x16 acc = zero16();
#pragma unroll
        for (int ds = 0; ds < 4; ++ds) {
          bf16x8 kf = *(const bf16x8*)(
              &sK[buf][(kh * 32 + c31) * KSTRIDE + ds * 16 + hi * 8]);
          acc = __builtin_amdgcn_mfma_f32_32x32x16_bf16(kf, qfrag[ds], acc, 0, 0, 0);
        }
        sc[kh] = acc;
      }
      __builtin_amdgcn_s_setprio(0);

      // window mask only on boundary tiles (wave-uniform branch)
      if (kk < q0 - 225 || kk > q0 + 193) {
        const int qa = q0 + c31;
#pragma unroll
        for (int kh = 0; kh < 2; ++kh)
#pragma unroll
          for (int r = 0; r < 16; ++r) {
            int key = kk + kh * 32 + (r & 3) + 8 * (r >> 2) + 4 * hi;
            unsigned dd = (unsigned)(key - qa + WIN_);
            if (dd > 2u * WIN_) sc[kh][r] = NEG_;
          }
      }

      // local tile max for this lane's q-column (keys split across hi-halves;
      // the __all ballot covers both halves, so no reduce on the defer path)
      float tl = NEG_;
#pragma unroll
      for (int kh = 0; kh < 2; ++kh)
#pragma unroll
        for (int r = 0; r < 16; r += 4)
          tl = fmaxf(tl, fmaxf(fmaxf(sc[kh][r], sc[kh][r + 1]),
                               fmaxf(sc[kh][r + 2], sc[kh][r + 3])));

      const bool defer = (__all(tl <= m + 8.0f) != 0);   // wave-uniform
      float mnew = m;
      if (!defer) {
        float tr = fmaxf(tl, __shfl_xor(tl, 32));
        mnew = fmaxf(m, tr);
      }

      // exp + pack + write P to per-wave LDS [q][key]
      float psum = 0.f;
#pragma unroll
      for (int kh = 0; kh < 2; ++kh)
#pragma unroll
        for (int g = 0; g < 4; ++g) {
          float p0 = exp2f(sc[kh][4 * g + 0] - mnew);
          float p1 = exp2f(sc[kh][4 * g + 1] - mnew);
          float p2 = exp2f(sc[kh][4 * g + 2] - mnew);
          float p3 = exp2f(sc[kh][4 * g + 3] - mnew);
          psum += (p0 + p1) + (p2 + p3);
          bf16x4 pk;
          pk[0] = (bf16_t)p0; pk[1] = (bf16_t)p1;
          pk[2] = (bf16_t)p2; pk[3] = (bf16_t)p3;
          // C row = (reg&3)+8*(reg>>2)+4*hi -> keys g*8+hi*4+{0..3} consecutive
          *(bf16x4*)(&plw[c31 * PSTRIDE + kh * 32 + g * 8 + hi * 4]) = pk;
        }

      if (!defer) {
        const float alq = exp2f(m - mnew);   // per-lane (q=c31), halves identical
#pragma unroll
        for (int r = 0; r < 16; ++r) {
          const int row = (r & 3) + 8 * (r >> 2) + 4 * hi;
          const float al = __shfl(alq, row);
          oacc[0][r] *= al; oacc[1][r] *= al;
        }
        el = el * alq + psum;
        m = mnew;
      } else {
        el += psum;
      }

      // wave-local drain: sP round-trip is per-wave
      asm volatile("s_waitcnt lgkmcnt(0)" ::: "memory");

      // P A-fragments: P[q=c31][key = ks*16 + hi*8 + e]
      bf16x8 pf[4];
#pragma unroll
      for (int ks = 0; ks < 4; ++ks)
        pf[ks] = *(const bf16x8*)(&plw[c31 * PSTRIDE + ks * 16 + hi * 8]);

      // O += P . V : full-rate 32x32x16, V^T from LDS (swizzled cols)
      __builtin_amdgcn_s_setprio(1);
#pragma unroll
      for (int dt = 0; dt < 2; ++dt) {
        const int d  = dt * 32 + c31;
        const int c8 = ((d >> 3) & 7) << 3;
#pragma unroll
        for (int ks = 0; ks < 4; ++ks) {
          bf16x8 vf = *(const bf16x8*)(
              &sVT[buf][d * VSTRIDE + ((ks * 16 + hi * 8) ^ c8)]);
          oacc[dt] = __builtin_amdgcn_mfma_f32_32x32x16_bf16(pf[ks], vf, oacc[dt], 0, 0, 0);
        }
      }
      __builtin_amdgcn_s_setprio(0);
    }

    __syncthreads();   // the single barrier per iteration
    buf ^= 1;
  }

  // ---- epilogue: merge hi/lo halves of the denominator, normalize, store ----
  el += __shfl_xor(el, 32);
  const float rlq = 1.0f / el;   // for q-column c31
#pragma unroll
  for (int r = 0; r < 16; ++r) {
    const int row = (r & 3) + 8 * (r >> 2) + 4 * hi;
    const float rl = __shfl(rlq, row);
    float* orow = outg + ((size_t)((b * SQ_ + q0 + row) * NH_ + h)) * DH_;
#pragma unroll
    for (int dt = 0; dt < 2; ++dt)
      orow[dt * 32 + c31] = oacc[dt][r] * rl;
  }
}

extern "C" void kernel_launch(void* const* d_in, const int* in_sizes, int n_in,
                              void* d_out, int out_size, void* d_ws, size_t ws_size,
                              hipStream_t stream) {
  (void)in_sizes; (void)n_in; (void)out_size; (void)d_ws; (void)ws_size;
  const float* q  = (const float*)d_in[0];
  const float* kv = (const float*)d_in[1];
  float* out = (float*)d_out;
  dim3 grid(B_ * NH_ * (SQ_ / 128));  // 512 blocks x 4 waves, 2 blocks/CU
  fa_fwd<<<grid, 256, 0, stream>>>(q, kv, out);
}